// Round 6
// baseline (119.744 us; speedup 1.0000x reference)
//
#include <hip/hip_runtime.h>
#include <math.h>

// ---------------------------------------------------------------------------
// PhysicsResonatorBank: B=8 notes, K=80 partials, NB=16 noise bands,
// N = n_frames*256 samples. out[b][c][n], c in {L,R}.
//
// Round-6 structure: single fused synth kernel, 512 threads = 8 waves;
// wave g owns k-chunk g (10 partials) for 64 samples x all 8 notes.
// NO LDS table staging: all per-k / per-(b,k) constants are wave-uniform
// and read straight from global (compiler emits s_load via the scalar
// pipe; table is 2.5 KB, sL1-resident). pk4 stored TRANSPOSED [k][b] so
// each k-iter reads 128 contiguous bytes. LDS only holds the cross-wave
// chunk-reduction buffer [8][64][17] (padded, conflict-free).
// Decay rates pre-scaled by log2(e) (exp2f = bare v_exp); beat freq in
// revolutions (v_cos direct). sin(phase) matches the reference's exact
// f32 phase fl(fl(2pi*f)*t) via 2-term Cody-Waite + __sinf.
// ---------------------------------------------------------------------------

#define NBMAX 32
#define NCH 8

#define C2PI_HI 6.28318548202514648f     // fl32(2*pi)
#define C2PI_LO -1.7484556e-7f           // fl32(2*pi - C2PI_HI)
#define INV2PI  0.15915494309189535f
#define LOG2E   1.44269504088896340736f

__device__ __forceinline__ float nofuse(float x) {
    asm volatile("" : "+v"(x));
    return x;
}

__device__ __forceinline__ float sin_cw(float ph) {
    float q = rintf(ph * INV2PI);
    float r = fmaf(q, -C2PI_HI, ph);
    r = fmaf(q, -C2PI_LO, r);
    return __sinf(r);
}

// ws layout (floats):
//  float4 pk4T[K*B] : [k][b] = {2pi*f, ampL, ampR, 0}
//  float4 keA[K]    : {log2e/tau1, log2e/tau2, a1, 1-a1}
//  float4 keB[K]    : {beat_hz (rev/s), 0.5*depth, 0, 0}
//  float4 nz [NB]   : {2pi*nf, band_gain, 0, 0}
//  float  nl [B]    : exp(log_noise_level)*vel ; nl[B] = 1/tau_noise

__global__ void pr_precomp(const float* __restrict__ f0,
                           const float* __restrict__ vel,
                           const float* __restrict__ pslope,
                           const float* __restrict__ pinter,
                           const float* __restrict__ log_tau1,
                           const float* __restrict__ log_tau2,
                           const float* __restrict__ logit_a1,
                           const float* __restrict__ log_beat_hz,
                           const float* __restrict__ logit_beat_depth,
                           const float* __restrict__ log_A0,
                           const float* __restrict__ harm_detune,
                           const float* __restrict__ noise_band_gain,
                           const float* __restrict__ plog_tau_noise,
                           const float* __restrict__ plog_noise_level,
                           const float* __restrict__ ppan_scale,
                           float* __restrict__ ws, int B, int K, int NB) {
    const int tid = threadIdx.x;
    const int b = blockIdx.x;           // grid = B blocks
    const float two_pi = C2PI_HI;
    const float slope = pslope[0], inter = pinter[0], pan_scale = ppan_scale[0];

    float4* pk4T = (float4*)ws;
    float4* keA = pk4T + (size_t)B * K;
    float4* keB = keA + K;
    float4* nz  = keB + K;
    float*  nl  = (float*)(nz + NB);

    // per-(b,k) oscillator constants: this block handles note b
    {
        float f0b = f0[b];
        float fr = f0b / 440.0f;
        float midi = 69.0f + 12.0f * (float)log2((double)fr);
        float mn = (midi - 21.0f) / 87.0f;
        float z = nofuse(slope * mn) + inter;
        z = fminf(fmaxf(z, -14.0f), -4.0f);
        float Binh = (float)exp((double)z);
        float pexp = (float)exp((double)pan_scale);
        int km1 = (K - 1) > 1 ? (K - 1) : 1;
        for (int k = tid; k < K; k += blockDim.x) {
            float kf = (float)(k + 1);
            float kk  = kf * kf;
            float bk2 = nofuse(Binh * kk);
            float arg = nofuse(1.0f + bk2);
            float s3  = (float)sqrt((double)arg);
            float r0  = nofuse(f0b * kf);
            float r1  = nofuse(r0 * s3);
            float dt  = nofuse(1.0f + harm_detune[k]);
            float fq  = nofuse(r1 * dt);
            float alive = (fq < 22050.0f) ? 1.0f : 0.0f;
            float amp = (float)exp((double)log_A0[k]) * vel[b] * alive;
            float a = (float)k / (float)km1;
            float pini = nofuse((a * 2.0f - 1.0f) * 0.1f);
            float pan = (float)tanh((double)nofuse(pini * pexp));
            float gl = (float)sqrt((double)(0.5f * (1.0f - pan)));
            float gr = (float)sqrt((double)(0.5f * (1.0f + pan)));
            float pf = nofuse(two_pi * fq);
            pk4T[(size_t)k * B + b] = make_float4(pf, amp * gl, amp * gr, 0.0f);
        }
    }

    if (b != 0) return;
    // shared (b-independent) tables: block 0 only
    for (int k = tid; k < K; k += blockDim.x) {
        float tau1 = (float)exp((double)log_tau1[k]);
        float tau2 = (float)exp((double)log_tau2[k]);
        float a1 = (float)(1.0 / (1.0 + exp(-(double)logit_a1[k])));
        float bhz = (float)exp((double)log_beat_hz[k]);
        float dep = (float)(1.0 / (1.0 + exp(-(double)logit_beat_depth[k])));
        keA[k] = make_float4(LOG2E / tau1, LOG2E / tau2, a1, 1.0f - a1);
        keB[k] = make_float4(bhz, 0.5f * dep, 0.0f, 0.0f);
    }
    for (int j = tid; j < NB; j += blockDim.x) {
        float m = -1e30f;
        for (int q = 0; q < NB; ++q) m = fmaxf(m, noise_band_gain[q]);
        float ssum = 0.0f;
        for (int q = 0; q < NB; ++q)
            ssum += (float)exp((double)(noise_band_gain[q] - m));
        double start = log(200.0), stop = log(20000.0);
        double step = (stop - start) / (double)(NB - 1);
        float lin = (j == NB - 1) ? (float)stop : (float)(start + (double)j * step);
        float nf = (float)exp((double)lin);
        float na = (nf < 22050.0f) ? 1.0f : 0.0f;
        float bg = ((float)exp((double)(noise_band_gain[j] - m)) / ssum) * na;
        nz[j] = make_float4(nofuse(two_pi * nf), bg, 0.0f, 0.0f);
    }
    for (int bb = tid; bb < B; bb += blockDim.x)
        nl[bb] = (float)exp((double)plog_noise_level[0]) * vel[bb];
    if (tid == 0) nl[B] = 1.0f / (float)exp((double)plog_tau_noise[0]);
}

// Fused synth: block = 64 samples x all notes; 8 waves = 8 K-chunks;
// LDS exchange + 8-way-split epilogue. All tables via scalar loads.
template <int BT>
__global__ __launch_bounds__(512, 8) void pr_synth(
    const float4* __restrict__ pk4T, const float4* __restrict__ keA,
    const float4* __restrict__ keB, const float4* __restrict__ nz,
    const float* __restrict__ nlp, float* __restrict__ out,
    int B, int K, int NB, int N) {
    __shared__ float s_red[NCH][64][2 * BT + 1];   // stride 17: conflict-free

    const int tid  = threadIdx.x;
    const int lane = tid & 63;
    const int g    = tid >> 6;          // wave index = k-chunk (0..7)

    const int n = blockIdx.x * 64 + lane;
    const float t = (float)n * (float)(1.0 / 44100.0);
    const float nt = -t;
    const int KC = (K + NCH - 1) / NCH;
    const int k0 = g * KC;
    const int k1 = min(K, k0 + KC);

    float accL[BT], accR[BT];
#pragma unroll
    for (int bi = 0; bi < BT; ++bi) { accL[bi] = 0.0f; accR[bi] = 0.0f; }

    for (int k = k0; k < k1; ++k) {
        float4 ka = keA[k];             // uniform -> s_load
        float4 kb = keB[k];
        float e1 = exp2f(nt * ka.x);
        float e2 = exp2f(nt * ka.y);
        float env = ka.z * e1 + ka.w * e2;
        float beat = fmaf(kb.y, __builtin_amdgcn_cosf(kb.x * t) - 1.0f, 1.0f);
        float eb = env * beat;
        const float4* pk = pk4T + (size_t)k * BT;
#pragma unroll
        for (int bi = 0; bi < BT; ++bi) {
            float4 p = pk[bi];          // uniform, contiguous -> s_load
            float ph = p.x * t;
            float q = rintf(ph * INV2PI);
            float r = fmaf(q, -C2PI_HI, ph);
            r = fmaf(q, -C2PI_LO, r);
            float sv = __sinf(r);
            float pp = eb * sv;
            accL[bi] = fmaf(p.y, pp, accL[bi]);
            accR[bi] = fmaf(p.z, pp, accR[bi]);
        }
    }

#pragma unroll
    for (int bi = 0; bi < BT; ++bi) {
        s_red[g][lane][2 * bi + 0] = accL[bi];
        s_red[g][lane][2 * bi + 1] = accR[bi];
    }
    __syncthreads();

    // attack noise (16 sins, redundant per wave)
    float ns = 0.0f;
    for (int j = 0; j < NB; ++j) {
        float4 zj = nz[j];              // uniform -> s_load
        ns = fmaf(zj.y, sin_cw(zj.x * t), ns);
    }
    float nsv = ns * __expf(nt * nlp[B]);

    const int JT = (2 * BT) / NCH;      // outputs per wave (2)
    if (n < N) {
#pragma unroll
        for (int jj = 0; jj < JT; ++jj) {
            int j = g * JT + jj;
            int b = j >> 1;
            if (b >= B) continue;
            float s = 0.0f;
#pragma unroll
            for (int c = 0; c < NCH; ++c) s += s_red[c][lane][j];
            float nois = nlp[b] * nsv;
            out[(size_t)j * N + n] = s + nois;
        }
    }
}

extern "C" void kernel_launch(void* const* d_in, const int* in_sizes, int n_in,
                              void* d_out, int out_size, void* d_ws, size_t ws_size,
                              hipStream_t stream) {
    const float* f0    = (const float*)d_in[0];
    const float* vel   = (const float*)d_in[1];
    const float* slope = (const float*)d_in[2];
    const float* inter = (const float*)d_in[3];
    const float* lt1   = (const float*)d_in[4];
    const float* lt2   = (const float*)d_in[5];
    const float* la1   = (const float*)d_in[6];
    const float* lbh   = (const float*)d_in[7];
    const float* lbd   = (const float*)d_in[8];
    const float* lA0   = (const float*)d_in[9];
    const float* hdet  = (const float*)d_in[10];
    const float* nbg   = (const float*)d_in[11];
    const float* ltn   = (const float*)d_in[12];
    const float* lnl   = (const float*)d_in[13];
    const float* pans  = (const float*)d_in[14];

    const int B  = in_sizes[0];
    const int K  = in_sizes[4];
    const int NB = in_sizes[11];
    const int N  = out_size / (2 * B);

    float* ws = (float*)d_ws;

    hipLaunchKernelGGL(pr_precomp, dim3(B), dim3(128), 0, stream,
                       f0, vel, slope, inter, lt1, lt2, la1, lbh, lbd, lA0,
                       hdet, nbg, ltn, lnl, pans, ws, B, K, NB);

    const float4* pk4T = (const float4*)ws;
    const float4* keA = pk4T + (size_t)B * K;
    const float4* keB = keA + K;
    const float4* nz  = keB + K;
    const float*  nlp = (const float*)(nz + NB);

    dim3 grid((N + 63) / 64);
    hipLaunchKernelGGL(pr_synth<8>, grid, dim3(512), 0, stream,
                       pk4T, keA, keB, nz, nlp, (float*)d_out, B, K, NB, N);
}

// Round 7
// 106.332 us; speedup vs baseline: 1.1261x; 1.1261x over previous
//
#include <hip/hip_runtime.h>
#include <math.h>

// ---------------------------------------------------------------------------
// PhysicsResonatorBank: B=8 notes, K=80 partials, NB=16 noise bands,
// N = n_frames*256 samples. out[b][c][n], c in {L,R}.
//
// Round-7 structure: single fused synth kernel, 512 threads = 8 waves;
// wave g owns k-chunk g (10 partials) for 64 samples x all 8 notes.
// KEY FIX vs round 6: g = readfirstlane(tid>>6) puts the chunk index in
// an SGPR, making every table address PROVABLY uniform -> the compiler
// emits s_load_dwordx4/x8 (SMEM pipe, sKcache-resident ~13 KB tables)
// instead of per-lane global_load (round 6's regression) or LDS
// broadcasts (round 5's bottleneck: ~200 ds_read_b128/wave on the
// shared LDS pipe). LDS now holds only the cross-wave reduction buffer
// [8][64][17] (padded, conflict-free).
// Per-k constants packed interleaved (ke8[2k],ke8[2k+1], 32 B stride);
// pk4 transposed [k][b] = 128 contiguous bytes per k-iter.
// Decay rates pre-scaled by log2(e) (exp2f = bare v_exp); beat freq in
// revolutions (v_cos direct). sin(phase) matches the reference's exact
// f32 phase fl(fl(2pi*f)*t) via 2-term Cody-Waite + __sinf.
// ---------------------------------------------------------------------------

#define NBMAX 32
#define NCH 8

#define C2PI_HI 6.28318548202514648f     // fl32(2*pi)
#define C2PI_LO -1.7484556e-7f           // fl32(2*pi - C2PI_HI)
#define INV2PI  0.15915494309189535f
#define LOG2E   1.44269504088896340736f

__device__ __forceinline__ float nofuse(float x) {
    asm volatile("" : "+v"(x));
    return x;
}

__device__ __forceinline__ float sin_cw(float ph) {
    float q = rintf(ph * INV2PI);
    float r = fmaf(q, -C2PI_HI, ph);
    r = fmaf(q, -C2PI_LO, r);
    return __sinf(r);
}

// ws layout (floats):
//  float4 pk4T[K*B] : [k][b] = {2pi*f, ampL, ampR, 0}
//  float4 ke8[2*K]  : [2k]   = {log2e/tau1, log2e/tau2, a1, 1-a1}
//                     [2k+1] = {beat_hz (rev/s), 0.5*depth, 0, 0}
//  float4 nz [NB]   : {2pi*nf, band_gain, 0, 0}
//  float  nl [B]    : exp(log_noise_level)*vel ; nl[B] = 1/tau_noise

__global__ void pr_precomp(const float* __restrict__ f0,
                           const float* __restrict__ vel,
                           const float* __restrict__ pslope,
                           const float* __restrict__ pinter,
                           const float* __restrict__ log_tau1,
                           const float* __restrict__ log_tau2,
                           const float* __restrict__ logit_a1,
                           const float* __restrict__ log_beat_hz,
                           const float* __restrict__ logit_beat_depth,
                           const float* __restrict__ log_A0,
                           const float* __restrict__ harm_detune,
                           const float* __restrict__ noise_band_gain,
                           const float* __restrict__ plog_tau_noise,
                           const float* __restrict__ plog_noise_level,
                           const float* __restrict__ ppan_scale,
                           float* __restrict__ ws, int B, int K, int NB) {
    const int tid = threadIdx.x;
    const int b = blockIdx.x;           // grid = B blocks
    const float two_pi = C2PI_HI;
    const float slope = pslope[0], inter = pinter[0], pan_scale = ppan_scale[0];

    float4* pk4T = (float4*)ws;
    float4* ke8 = pk4T + (size_t)B * K;
    float4* nz  = ke8 + 2 * K;
    float*  nl  = (float*)(nz + NB);

    // per-(b,k) oscillator constants: this block handles note b
    {
        float f0b = f0[b];
        float fr = f0b / 440.0f;
        float midi = 69.0f + 12.0f * (float)log2((double)fr);
        float mn = (midi - 21.0f) / 87.0f;
        float z = nofuse(slope * mn) + inter;
        z = fminf(fmaxf(z, -14.0f), -4.0f);
        float Binh = (float)exp((double)z);
        float pexp = (float)exp((double)pan_scale);
        int km1 = (K - 1) > 1 ? (K - 1) : 1;
        for (int k = tid; k < K; k += blockDim.x) {
            float kf = (float)(k + 1);
            float kk  = kf * kf;
            float bk2 = nofuse(Binh * kk);
            float arg = nofuse(1.0f + bk2);
            float s3  = (float)sqrt((double)arg);
            float r0  = nofuse(f0b * kf);
            float r1  = nofuse(r0 * s3);
            float dt  = nofuse(1.0f + harm_detune[k]);
            float fq  = nofuse(r1 * dt);
            float alive = (fq < 22050.0f) ? 1.0f : 0.0f;
            float amp = (float)exp((double)log_A0[k]) * vel[b] * alive;
            float a = (float)k / (float)km1;
            float pini = nofuse((a * 2.0f - 1.0f) * 0.1f);
            float pan = (float)tanh((double)nofuse(pini * pexp));
            float gl = (float)sqrt((double)(0.5f * (1.0f - pan)));
            float gr = (float)sqrt((double)(0.5f * (1.0f + pan)));
            float pf = nofuse(two_pi * fq);
            pk4T[(size_t)k * B + b] = make_float4(pf, amp * gl, amp * gr, 0.0f);
        }
    }

    if (b != 0) return;
    // shared (b-independent) tables: block 0 only
    for (int k = tid; k < K; k += blockDim.x) {
        float tau1 = (float)exp((double)log_tau1[k]);
        float tau2 = (float)exp((double)log_tau2[k]);
        float a1 = (float)(1.0 / (1.0 + exp(-(double)logit_a1[k])));
        float bhz = (float)exp((double)log_beat_hz[k]);
        float dep = (float)(1.0 / (1.0 + exp(-(double)logit_beat_depth[k])));
        ke8[2 * k]     = make_float4(LOG2E / tau1, LOG2E / tau2, a1, 1.0f - a1);
        ke8[2 * k + 1] = make_float4(bhz, 0.5f * dep, 0.0f, 0.0f);
    }
    for (int j = tid; j < NB; j += blockDim.x) {
        float m = -1e30f;
        for (int q = 0; q < NB; ++q) m = fmaxf(m, noise_band_gain[q]);
        float ssum = 0.0f;
        for (int q = 0; q < NB; ++q)
            ssum += (float)exp((double)(noise_band_gain[q] - m));
        double start = log(200.0), stop = log(20000.0);
        double step = (stop - start) / (double)(NB - 1);
        float lin = (j == NB - 1) ? (float)stop : (float)(start + (double)j * step);
        float nf = (float)exp((double)lin);
        float na = (nf < 22050.0f) ? 1.0f : 0.0f;
        float bg = ((float)exp((double)(noise_band_gain[j] - m)) / ssum) * na;
        nz[j] = make_float4(nofuse(two_pi * nf), bg, 0.0f, 0.0f);
    }
    for (int bb = tid; bb < B; bb += blockDim.x)
        nl[bb] = (float)exp((double)plog_noise_level[0]) * vel[bb];
    if (tid == 0) nl[B] = 1.0f / (float)exp((double)plog_tau_noise[0]);
}

// Fused synth: block = 64 samples x all notes; 8 waves = 8 K-chunks;
// LDS exchange + 8-way-split epilogue. All tables via SCALAR loads
// (indices derived from readfirstlane -> SGPR -> s_load).
template <int BT>
__global__ __launch_bounds__(512, 8) void pr_synth(
    const float4* __restrict__ pk4T, const float4* __restrict__ ke8,
    const float4* __restrict__ nz, const float* __restrict__ nlp,
    float* __restrict__ out, int B, int K, int NB, int N) {
    __shared__ float s_red[NCH][64][2 * BT + 1];   // stride 17: conflict-free

    const int tid  = threadIdx.x;
    const int lane = tid & 63;
    // SGPR wave index -> all table addresses provably uniform -> s_load
    const int g    = __builtin_amdgcn_readfirstlane(tid >> 6);

    const int n = blockIdx.x * 64 + lane;
    const float t = (float)n * (float)(1.0 / 44100.0);
    const float nt = -t;
    const int KC = (K + NCH - 1) / NCH;
    const int k0 = g * KC;
    const int k1 = min(K, k0 + KC);

    float accL[BT], accR[BT];
#pragma unroll
    for (int bi = 0; bi < BT; ++bi) { accL[bi] = 0.0f; accR[bi] = 0.0f; }

    for (int k = k0; k < k1; ++k) {
        float4 ka = ke8[2 * k];         // uniform -> s_load_dwordx8
        float4 kb = ke8[2 * k + 1];
        float e1 = exp2f(nt * ka.x);
        float e2 = exp2f(nt * ka.y);
        float env = ka.z * e1 + ka.w * e2;
        float beat = fmaf(kb.y, __builtin_amdgcn_cosf(kb.x * t) - 1.0f, 1.0f);
        float eb = env * beat;
        const float4* pk = pk4T + (size_t)k * BT;
#pragma unroll
        for (int bi = 0; bi < BT; ++bi) {
            float4 p = pk[bi];          // uniform, 128B contiguous -> s_load
            float ph = p.x * t;
            float q = rintf(ph * INV2PI);
            float r = fmaf(q, -C2PI_HI, ph);
            r = fmaf(q, -C2PI_LO, r);
            float sv = __sinf(r);
            float pp = eb * sv;
            accL[bi] = fmaf(p.y, pp, accL[bi]);
            accR[bi] = fmaf(p.z, pp, accR[bi]);
        }
    }

#pragma unroll
    for (int bi = 0; bi < BT; ++bi) {
        s_red[g][lane][2 * bi + 0] = accL[bi];
        s_red[g][lane][2 * bi + 1] = accR[bi];
    }
    __syncthreads();

    // attack noise (16 sins, redundant per wave; all table reads scalar)
    float ns = 0.0f;
    for (int j = 0; j < NB; ++j) {
        float4 zj = nz[j];              // uniform -> s_load
        ns = fmaf(zj.y, sin_cw(zj.x * t), ns);
    }
    float nsv = ns * __expf(nt * nlp[B]);

    const int JT = (2 * BT) / NCH;      // outputs per wave (2)
    if (n < N) {
#pragma unroll
        for (int jj = 0; jj < JT; ++jj) {
            int j = g * JT + jj;
            int b = j >> 1;
            if (b >= B) continue;
            float s = 0.0f;
#pragma unroll
            for (int c = 0; c < NCH; ++c) s += s_red[c][lane][j];
            float nois = nlp[b] * nsv;
            out[(size_t)j * N + n] = s + nois;
        }
    }
}

extern "C" void kernel_launch(void* const* d_in, const int* in_sizes, int n_in,
                              void* d_out, int out_size, void* d_ws, size_t ws_size,
                              hipStream_t stream) {
    const float* f0    = (const float*)d_in[0];
    const float* vel   = (const float*)d_in[1];
    const float* slope = (const float*)d_in[2];
    const float* inter = (const float*)d_in[3];
    const float* lt1   = (const float*)d_in[4];
    const float* lt2   = (const float*)d_in[5];
    const float* la1   = (const float*)d_in[6];
    const float* lbh   = (const float*)d_in[7];
    const float* lbd   = (const float*)d_in[8];
    const float* lA0   = (const float*)d_in[9];
    const float* hdet  = (const float*)d_in[10];
    const float* nbg   = (const float*)d_in[11];
    const float* ltn   = (const float*)d_in[12];
    const float* lnl   = (const float*)d_in[13];
    const float* pans  = (const float*)d_in[14];

    const int B  = in_sizes[0];
    const int K  = in_sizes[4];
    const int NB = in_sizes[11];
    const int N  = out_size / (2 * B);

    float* ws = (float*)d_ws;

    hipLaunchKernelGGL(pr_precomp, dim3(B), dim3(128), 0, stream,
                       f0, vel, slope, inter, lt1, lt2, la1, lbh, lbd, lA0,
                       hdet, nbg, ltn, lnl, pans, ws, B, K, NB);

    const float4* pk4T = (const float4*)ws;
    const float4* ke8 = pk4T + (size_t)B * K;
    const float4* nz  = ke8 + 2 * K;
    const float*  nlp = (const float*)(nz + NB);

    dim3 grid((N + 63) / 64);
    hipLaunchKernelGGL(pr_synth<8>, grid, dim3(512), 0, stream,
                       pk4T, ke8, nz, nlp, (float*)d_out, B, K, NB, N);
}